// Round 14
// baseline (131.919 us; speedup 1.0000x reference)
//
#include <hip/hip_runtime.h>
#include <math.h>

#define B_ 16
#define T_ 24
#define N_ 300
#define E_ 9600
#define H_ 3
#define F_ 8
#define HF_ 24
#define GRUH_ 16
#define OUTB_ 7200   // NUM_AIRPORTS * HORIZON
#define CPB_ 2       // chunks (blocks) per graph
#define NPC_ 150     // nodes per chunk
#define NW_ 16       // waves in csr block

// ====== K1: CSR build with per-wave sub-histograms ==================================
__global__ __launch_bounds__(1024) void csr_kernel(
    const int* __restrict__ src, const int* __restrict__ dst,
    int* __restrict__ rp, unsigned* __restrict__ pk)
{
    __shared__ int cnt[NW_ * N_];   // per-wave histograms -> per-wave exclusive prefixes
    __shared__ int tot[N_];
    __shared__ int rps[N_ + 1];
    const int tid = threadIdx.x;
    const int w = tid >> 6;

    for (int i = tid; i < NW_ * N_; i += 1024) cnt[i] = 0;
    __syncthreads();
    for (int i = tid; i < E_; i += 1024) atomicAdd(&cnt[w * N_ + dst[i]], 1);
    __syncthreads();
    if (tid < N_) {
        int run = 0;
        #pragma unroll
        for (int k = 0; k < NW_; ++k) {
            int t = cnt[k * N_ + tid];
            cnt[k * N_ + tid] = run;
            run += t;
        }
        tot[tid] = run;
    }
    __syncthreads();
    if (tid < 64) {
        int base = 0;
        for (int c = 0; c < 5; ++c) {
            int i = c * 64 + tid;
            int orig = (i < N_) ? tot[i] : 0;
            int v = orig;
            #pragma unroll
            for (int o = 1; o < 64; o <<= 1) {
                int u = __shfl_up(v, o, 64);
                if (tid >= o) v += u;
            }
            if (i < N_) rps[i] = base + v - orig;
            base += __shfl(v, 63, 64);
        }
        if (tid == 0) rps[N_] = base;
    }
    __syncthreads();
    for (int i = tid; i <= N_; i += 1024) rp[i] = rps[i];
    for (int i = tid; i < E_; i += 1024) {
        int d = dst[i];
        int pos = rps[d] + atomicAdd(&cnt[w * N_ + d], 1);
        pk[pos] = (unsigned)i | ((unsigned)src[i] << 17);
    }
}

// ====== K2: EdgeGAT partial sums; 2 blocks/graph, heads fused, XCD swizzle ==========
__global__ __launch_bounds__(320) void gat_kernel(
    const float* __restrict__ x, const float* __restrict__ ew,
    const float* __restrict__ Wn, const float* __restrict__ We,
    const float* __restrict__ al, const float* __restrict__ ar,
    const float* __restrict__ ae,
    const int* __restrict__ rp_g, const unsigned* __restrict__ pk_g,
    float* __restrict__ Spart)
{
    __shared__ float xs[N_];
    __shared__ int rp_l[N_ + 1];
    __shared__ float cf[9];
    __shared__ float Sred[5][3];

    const int L = blockIdx.x;
    const int m = L >> 3;
    const int c = m & 1;
    const int g = (L & 7) + 8 * (m >> 1);
    const int tid = threadIdx.x;
    const long base_e = (long)g * E_;
    const int  base_n = g * N_;

    for (int i = tid; i < N_; i += 320) xs[i] = x[base_n + i];
    for (int i = tid; i <= N_; i += 320) rp_l[i] = rp_g[i];
    if (tid < H_) {
        int h = tid;
        float cl = 0.f, cr = 0.f, ce = 0.f;
        #pragma unroll
        for (int f = 0; f < F_; ++f) {
            float wn = Wn[h * F_ + f];
            cl += wn * al[h * F_ + f];
            cr += wn * ar[h * F_ + f];
            ce += We[h * F_ + f] * ae[h * F_ + f];
        }
        cf[h] = cl; cf[3 + h] = cr; cf[6 + h] = ce;
    }
    __syncthreads();

    float n0 = 0.f, d0 = 0.f, n1 = 0.f, d1 = 0.f, n2 = 0.f, d2 = 0.f;
    if (tid < 2 * NPC_) {
        const int n = c * NPC_ + (tid >> 1);
        const int half = tid & 1;
        const float xd = xs[n];
        const float c0l = cf[0], c1l = cf[1], c2l = cf[2];
        const float c0r = cf[3], c1r = cf[4], c2r = cf[5];
        const float c0e = cf[6], c1e = cf[7], c2e = cf[8];
        const int p1 = rp_l[n + 1];
        for (int p = rp_l[n] + half; p < p1; p += 2) {
            unsigned pkv = pk_g[p];
            float w = ew[base_e + (pkv & 0x1FFFFu)];
            float xsv = xs[pkv >> 17];
            float e0 = fmaf(xsv, c0l, fmaf(xd, c0r, w * c0e)); e0 = e0 > 0.f ? e0 : 0.2f * e0;
            float e1 = fmaf(xsv, c1l, fmaf(xd, c1r, w * c1e)); e1 = e1 > 0.f ? e1 : 0.2f * e1;
            float e2 = fmaf(xsv, c2l, fmaf(xd, c2r, w * c2e)); e2 = e2 > 0.f ? e2 : 0.2f * e2;
            float p0 = __expf(e0), pe1 = __expf(e1), pe2 = __expf(e2);
            d0 += p0;  n0 += p0 * xsv;
            d1 += pe1; n1 += pe1 * xsv;
            d2 += pe2; n2 += pe2 * xsv;
        }
    }
    n0 += __shfl_xor(n0, 1); d0 += __shfl_xor(d0, 1);
    n1 += __shfl_xor(n1, 1); d1 += __shfl_xor(d1, 1);
    n2 += __shfl_xor(n2, 1); d2 += __shfl_xor(d2, 1);
    float a0 = 0.f, a1 = 0.f, a2 = 0.f;
    if (tid < 2 * NPC_ && (tid & 1) == 0) {
        a0 = d0 > 0.f ? n0 / d0 : 0.f;
        a1 = d1 > 0.f ? n1 / d1 : 0.f;
        a2 = d2 > 0.f ? n2 / d2 : 0.f;
    }
    for (int o = 32; o; o >>= 1) {
        a0 += __shfl_down(a0, o);
        a1 += __shfl_down(a1, o);
        a2 += __shfl_down(a2, o);
    }
    const int wave = tid >> 6, lane = tid & 63;
    if (lane == 0) { Sred[wave][0] = a0; Sred[wave][1] = a1; Sred[wave][2] = a2; }
    __syncthreads();
    if (tid < 3)
        Spart[g * (CPB_ * 3) + c * 3 + tid] =
            Sred[0][tid] + Sred[1][tid] + Sred[2][tid] + Sred[3][tid] + Sred[4][tid];
}

// ====== K3: FC with replicated-GRU prologue ==========================================
__global__ __launch_bounds__(256) void fc_kernel(
    const float* __restrict__ Spart, const float* __restrict__ Wn,
    const float* __restrict__ gb, const float* __restrict__ Wih,
    const float* __restrict__ bih, const float* __restrict__ Whh,
    const float* __restrict__ bhh, const float* __restrict__ Wfc,
    const float* __restrict__ bfc, float* __restrict__ out)
{
    __shared__ float hS[2][GRUH_];
    const int tid = threadIdx.x;
    const int idx0 = blockIdx.x * 256;
    const int b0 = idx0 / OUTB_;

    if (tid < 64) {
        const int grp = tid >> 4;
        const int u = tid & 15;
        const int gbase = tid & ~15;
        const bool active = (grp < 2) && (b0 + grp < B_);
        const int bb = active ? (b0 + grp) : b0;

        float whr[GRUH_], whz[GRUH_], whn[GRUH_];
        #pragma unroll
        for (int k = 0; k < GRUH_; ++k) {
            whr[k] = Whh[u * GRUH_ + k];
            whz[k] = Whh[(16 + u) * GRUH_ + k];
            whn[k] = Whh[(32 + u) * GRUH_ + k];
        }
        const float bhr = bhh[u], bhz = bhh[16 + u], bhn = bhh[32 + u];

        float A[3][3], C[3];
        #pragma unroll
        for (int r = 0; r < 3; ++r) {
            const int j = r * 16 + u;
            float cc = bih[j];
            A[r][0] = A[r][1] = A[r][2] = 0.f;
            #pragma unroll
            for (int k = 0; k < HF_; ++k) {
                float wk = Wih[j * HF_ + k];
                cc += wk * gb[k];
                A[r][k >> 3] += wk * Wn[k];
            }
            C[r] = cc;
        }

        float h = 0.f;
        for (int t = 0; t < T_; ++t) {
            const float* sp = Spart + (bb * T_ + t) * (CPB_ * 3);
            float S0 = (sp[0] + sp[3]) * (1.0f / N_);
            float S1 = (sp[1] + sp[4]) * (1.0f / N_);
            float S2 = (sp[2] + sp[5]) * (1.0f / N_);
            float gr = C[0] + A[0][0] * S0 + A[0][1] * S1 + A[0][2] * S2;
            float gz = C[1] + A[1][0] * S0 + A[1][1] * S1 + A[1][2] * S2;
            float gn = C[2] + A[2][0] * S0 + A[2][1] * S1 + A[2][2] * S2;
            float hr = bhr, hz = bhz, hn = bhn;
            #pragma unroll
            for (int k = 0; k < GRUH_; ++k) {
                float hk = __shfl(h, gbase + k, 64);
                hr += whr[k] * hk;
                hz += whz[k] * hk;
                hn += whn[k] * hk;
            }
            float r = 1.f / (1.f + __expf(-(gr + hr)));
            float z = 1.f / (1.f + __expf(-(gz + hz)));
            float n = tanhf(gn + r * hn);
            h = (1.f - z) * n + z * h;
        }
        if (active) hS[grp][u] = h;
    }
    __syncthreads();

    const int idx = idx0 + tid;
    if (idx < B_ * OUTB_) {
        const int b = idx / OUTB_, o = idx - b * OUTB_;
        const float4* wr = (const float4*)(Wfc + (long)o * GRUH_);
        const float* hr = hS[b - b0];
        float4 w0 = wr[0], w1 = wr[1], w2 = wr[2], w3 = wr[3];
        float acc = bfc[o];
        acc += hr[0]  * w0.x + hr[1]  * w0.y + hr[2]  * w0.z + hr[3]  * w0.w;
        acc += hr[4]  * w1.x + hr[5]  * w1.y + hr[6]  * w1.z + hr[7]  * w1.w;
        acc += hr[8]  * w2.x + hr[9]  * w2.y + hr[10] * w2.z + hr[11] * w2.w;
        acc += hr[12] * w3.x + hr[13] * w3.y + hr[14] * w3.z + hr[15] * w3.w;
        out[idx] = acc;
    }
}

extern "C" void kernel_launch(void* const* d_in, const int* in_sizes, int n_in,
                              void* d_out, int out_size, void* d_ws, size_t ws_size,
                              hipStream_t stream) {
    const float* x    = (const float*)d_in[0];
    const float* ew   = (const float*)d_in[1];
    const float* Wn   = (const float*)d_in[2];
    const float* We   = (const float*)d_in[3];
    const float* al   = (const float*)d_in[4];
    const float* ar   = (const float*)d_in[5];
    const float* ae   = (const float*)d_in[6];
    const float* gb   = (const float*)d_in[7];
    const float* Wih  = (const float*)d_in[8];
    const float* Whh  = (const float*)d_in[9];
    const float* bih  = (const float*)d_in[10];
    const float* bhh  = (const float*)d_in[11];
    const float* Wfc  = (const float*)d_in[12];
    const float* bfc  = (const float*)d_in[13];
    const int*   src  = (const int*)d_in[14];
    const int*   dst  = (const int*)d_in[15];
    float* out = (float*)d_out;

    // ws layout
    int* rp = (int*)d_ws;                               // [301] (pad to 320)
    unsigned* pk = (unsigned*)(rp + 320);               // [9600]
    float* Spart = (float*)(pk + E_);                   // [384*2*3]

    // DIAGNOSTIC: csr x10 (idempotent). csr+gap = (total_R14 - total_R12) / 9.
    for (int rep = 0; rep < 10; ++rep)
        csr_kernel<<<1, 1024, 0, stream>>>(src, dst, rp, pk);
    gat_kernel<<<B_ * T_ * CPB_, 320, 0, stream>>>(x, ew, Wn, We, al, ar, ae,
                                                   rp, pk, Spart);
    fc_kernel<<<(B_ * OUTB_ + 255) / 256, 256, 0, stream>>>(Spart, Wn, gb, Wih, bih,
                                                            Whh, bhh, Wfc, bfc, out);
}

// Round 15
// 71.930 us; speedup vs baseline: 1.8340x; 1.8340x over previous
//
#include <hip/hip_runtime.h>
#include <math.h>

#define B_ 16
#define T_ 24
#define G_ 384        // B*T graphs
#define N_ 300
#define E_ 9600
#define H_ 3
#define F_ 8
#define HF_ 24
#define GRUH_ 16
#define OUTB_ 7200    // NUM_AIRPORTS * HORIZON
#define NW_ 16        // waves in csr block
#define NG_ 6         // graph groups of 64
#define ROWS_ 8       // node rows per gat block
#define NCH_ 38       // ceil(N_/ROWS_)

// ====== K1: blocks 0..899 transpose ew->ewT; block 900 builds CSR (concurrent) ======
__global__ __launch_bounds__(1024) void prep_kernel(
    const float* __restrict__ ew, const int* __restrict__ src, const int* __restrict__ dst,
    float* __restrict__ ewT, int* __restrict__ rp, unsigned* __restrict__ pk)
{
    const int tid = threadIdx.x;
    if (blockIdx.x < 900) {
        __shared__ float tile[64][65];
        const int rt = blockIdx.x / 150, ct = blockIdx.x - rt * 150;
        const int r0 = rt * 64, c0 = ct * 64;
        const int tx = tid & 63, ty = tid >> 6;          // ty 0..15
        #pragma unroll
        for (int k = 0; k < 4; ++k) {
            int r = ty * 4 + k;
            tile[r][tx] = ew[(long)(r0 + r) * E_ + c0 + tx];
        }
        __syncthreads();
        #pragma unroll
        for (int k = 0; k < 4; ++k) {
            int r = ty * 4 + k;
            ewT[(long)(c0 + r) * G_ + r0 + tx] = tile[tx][r];
        }
    } else {
        __shared__ int cnt[NW_ * N_];
        __shared__ int tot[N_];
        __shared__ int rps[N_ + 1];
        const int w = tid >> 6;
        for (int i = tid; i < NW_ * N_; i += 1024) cnt[i] = 0;
        __syncthreads();
        for (int i = tid; i < E_; i += 1024) atomicAdd(&cnt[w * N_ + dst[i]], 1);
        __syncthreads();
        if (tid < N_) {
            int run = 0;
            #pragma unroll
            for (int k = 0; k < NW_; ++k) {
                int t = cnt[k * N_ + tid];
                cnt[k * N_ + tid] = run;
                run += t;
            }
            tot[tid] = run;
        }
        __syncthreads();
        if (tid < 64) {
            int base = 0;
            for (int c = 0; c < 5; ++c) {
                int i = c * 64 + tid;
                int orig = (i < N_) ? tot[i] : 0;
                int v = orig;
                #pragma unroll
                for (int o = 1; o < 64; o <<= 1) {
                    int u = __shfl_up(v, o, 64);
                    if (tid >= o) v += u;
                }
                if (i < N_) rps[i] = base + v - orig;
                base += __shfl(v, 63, 64);
            }
            if (tid == 0) rps[N_] = base;
        }
        __syncthreads();
        for (int i = tid; i <= N_; i += 1024) rp[i] = rps[i];
        for (int i = tid; i < E_; i += 1024) {
            int d = dst[i];
            int pos = rps[d] + atomicAdd(&cnt[w * N_ + d], 1);
            pk[pos] = (unsigned)i | ((unsigned)src[i] << 17);
        }
    }
}

// ====== K2: EdgeGAT, lane = graph: pk broadcast + coalesced ewT + LDS xsT ===========
__global__ __launch_bounds__(512) void gat_kernel(
    const float* __restrict__ x, const float* __restrict__ ewT,
    const float* __restrict__ Wn, const float* __restrict__ We,
    const float* __restrict__ al, const float* __restrict__ ar,
    const float* __restrict__ ae,
    const int* __restrict__ rp, const unsigned* __restrict__ pk,
    float* __restrict__ Spart)
{
    __shared__ float xsT[N_ * 64];     // [n][j], j XOR-swizzled by (n&31): conflict-free
    __shared__ float red[ROWS_ * 64 * H_];
    __shared__ float cf[9];

    const int ggrp = blockIdx.x / NCH_;        // 0..5
    const int chunk = blockIdx.x - ggrp * NCH_;// 0..37
    const int g0 = ggrp * 64;
    const int tid = threadIdx.x;
    const int lane = tid & 63;                 // graph within group
    const int ty = tid >> 6;                   // node row 0..7

    for (int idx = tid; idx < 64 * N_; idx += 512) {
        int j = idx / N_, n = idx - j * N_;
        xsT[n * 64 + (j ^ (n & 31))] = x[(long)(g0 + j) * N_ + n];
    }
    if (tid < H_) {
        int h = tid;
        float cl = 0.f, cr = 0.f, ce = 0.f;
        #pragma unroll
        for (int f = 0; f < F_; ++f) {
            float wn = Wn[h * F_ + f];
            cl += wn * al[h * F_ + f];
            cr += wn * ar[h * F_ + f];
            ce += We[h * F_ + f] * ae[h * F_ + f];
        }
        cf[h] = cl; cf[3 + h] = cr; cf[6 + h] = ce;
    }
    __syncthreads();

    const int n = chunk * ROWS_ + ty;
    float a0 = 0.f, a1 = 0.f, a2 = 0.f;
    if (n < N_) {
        const float c0l = cf[0], c1l = cf[1], c2l = cf[2];
        const float c0r = cf[3], c1r = cf[4], c2r = cf[5];
        const float c0e = cf[6], c1e = cf[7], c2e = cf[8];
        const float xd = xsT[n * 64 + (lane ^ (n & 31))];
        const int p0 = rp[n], p1 = rp[n + 1];
        float n0 = 0.f, d0 = 0.f, n1 = 0.f, d1 = 0.f, n2 = 0.f, d2 = 0.f;
        for (int p = p0; p < p1; ++p) {
            unsigned pkv = pk[p];               // wave-uniform broadcast
            int eidx = pkv & 0x1FFFF;
            int s = pkv >> 17;
            float w = ewT[(long)eidx * G_ + g0 + lane];    // coalesced 256B
            float xsv = xsT[s * 64 + (lane ^ (s & 31))];   // LDS, conflict-free
            float e0 = fmaf(xsv, c0l, fmaf(xd, c0r, w * c0e)); e0 = e0 > 0.f ? e0 : 0.2f * e0;
            float e1 = fmaf(xsv, c1l, fmaf(xd, c1r, w * c1e)); e1 = e1 > 0.f ? e1 : 0.2f * e1;
            float e2 = fmaf(xsv, c2l, fmaf(xd, c2r, w * c2e)); e2 = e2 > 0.f ? e2 : 0.2f * e2;
            float p0e = __expf(e0), p1e = __expf(e1), p2e = __expf(e2);
            d0 += p0e; n0 += p0e * xsv;
            d1 += p1e; n1 += p1e * xsv;
            d2 += p2e; n2 += p2e * xsv;
        }
        a0 = d0 > 0.f ? n0 / d0 : 0.f;
        a1 = d1 > 0.f ? n1 / d1 : 0.f;
        a2 = d2 > 0.f ? n2 / d2 : 0.f;
    }
    red[(ty * 64 + lane) * 3 + 0] = a0;
    red[(ty * 64 + lane) * 3 + 1] = a1;
    red[(ty * 64 + lane) * 3 + 2] = a2;
    __syncthreads();
    // sum over the 8 node-rows; write 192 floats for this (chunk, group)
    for (int idx = tid; idx < 64 * H_; idx += 512) {
        float s = 0.f;
        #pragma unroll
        for (int r = 0; r < ROWS_; ++r) s += red[r * 192 + idx];
        Spart[(long)chunk * (G_ * H_) + (long)g0 * H_ + idx] = s;
    }
}

// ====== K3: FC with chunk-reduce + replicated-GRU prologue ==========================
__global__ __launch_bounds__(256) void fc_kernel(
    const float* __restrict__ Spart, const float* __restrict__ Wn,
    const float* __restrict__ gb, const float* __restrict__ Wih,
    const float* __restrict__ bih, const float* __restrict__ Whh,
    const float* __restrict__ bhh, const float* __restrict__ Wfc,
    const float* __restrict__ bfc, float* __restrict__ out)
{
    __shared__ float S2[2][T_][H_];   // per-block: S for its (up to) 2 batches, /N
    __shared__ float hS[2][GRUH_];
    const int tid = threadIdx.x;
    const int idx0 = blockIdx.x * 256;
    const int b0 = idx0 / OUTB_;

    // chunk-reduce: thread i < 144 owns (grp, t, h); sums 38 chunk partials (L2-hot)
    if (tid < 2 * T_ * H_) {
        const int grp = tid / (T_ * H_);
        const int rem = tid - grp * (T_ * H_);
        const int t = rem / H_, h = rem - t * H_;
        const int bb = b0 + grp;
        float s = 0.f;
        if (bb < B_) {
            const int gh = (bb * T_ + t) * H_ + h;
            #pragma unroll 2
            for (int c = 0; c < NCH_; ++c) s += Spart[(long)c * (G_ * H_) + gh];
        }
        S2[grp][t][h] = s * (1.0f / N_);
    }
    __syncthreads();

    if (tid < 64) {
        const int grp = tid >> 4;            // 0..3 (only 0,1 used)
        const int u = tid & 15;
        const int gbase = tid & ~15;
        const bool active = (grp < 2) && (b0 + grp < B_);
        const int sgrp = active ? grp : 0;

        float whr[GRUH_], whz[GRUH_], whn[GRUH_];
        #pragma unroll
        for (int k = 0; k < GRUH_; ++k) {
            whr[k] = Whh[u * GRUH_ + k];
            whz[k] = Whh[(16 + u) * GRUH_ + k];
            whn[k] = Whh[(32 + u) * GRUH_ + k];
        }
        const float bhr = bhh[u], bhz = bhh[16 + u], bhn = bhh[32 + u];

        float A[3][3], C[3];
        #pragma unroll
        for (int r = 0; r < 3; ++r) {
            const int j = r * 16 + u;
            float cc = bih[j];
            A[r][0] = A[r][1] = A[r][2] = 0.f;
            #pragma unroll
            for (int k = 0; k < HF_; ++k) {
                float wk = Wih[j * HF_ + k];
                cc += wk * gb[k];
                A[r][k >> 3] += wk * Wn[k];
            }
            C[r] = cc;
        }

        float h = 0.f;
        for (int t = 0; t < T_; ++t) {
            float S0 = S2[sgrp][t][0], S1 = S2[sgrp][t][1], Sv2 = S2[sgrp][t][2];
            float gr = C[0] + A[0][0] * S0 + A[0][1] * S1 + A[0][2] * Sv2;
            float gz = C[1] + A[1][0] * S0 + A[1][1] * S1 + A[1][2] * Sv2;
            float gn = C[2] + A[2][0] * S0 + A[2][1] * S1 + A[2][2] * Sv2;
            float hr = bhr, hz = bhz, hn = bhn;
            #pragma unroll
            for (int k = 0; k < GRUH_; ++k) {
                float hk = __shfl(h, gbase + k, 64);
                hr += whr[k] * hk;
                hz += whz[k] * hk;
                hn += whn[k] * hk;
            }
            float r = 1.f / (1.f + __expf(-(gr + hr)));
            float z = 1.f / (1.f + __expf(-(gz + hz)));
            float nn = tanhf(gn + r * hn);
            h = (1.f - z) * nn + z * h;
        }
        if (active) hS[grp][u] = h;
    }
    __syncthreads();

    const int idx = idx0 + tid;
    if (idx < B_ * OUTB_) {
        const int b = idx / OUTB_, o = idx - b * OUTB_;
        const float4* wr = (const float4*)(Wfc + (long)o * GRUH_);
        const float* hr = hS[b - b0];
        float4 w0 = wr[0], w1 = wr[1], w2 = wr[2], w3 = wr[3];
        float acc = bfc[o];
        acc += hr[0]  * w0.x + hr[1]  * w0.y + hr[2]  * w0.z + hr[3]  * w0.w;
        acc += hr[4]  * w1.x + hr[5]  * w1.y + hr[6]  * w1.z + hr[7]  * w1.w;
        acc += hr[8]  * w2.x + hr[9]  * w2.y + hr[10] * w2.z + hr[11] * w2.w;
        acc += hr[12] * w3.x + hr[13] * w3.y + hr[14] * w3.z + hr[15] * w3.w;
        out[idx] = acc;
    }
}

extern "C" void kernel_launch(void* const* d_in, const int* in_sizes, int n_in,
                              void* d_out, int out_size, void* d_ws, size_t ws_size,
                              hipStream_t stream) {
    const float* x    = (const float*)d_in[0];
    const float* ew   = (const float*)d_in[1];
    const float* Wn   = (const float*)d_in[2];
    const float* We   = (const float*)d_in[3];
    const float* al   = (const float*)d_in[4];
    const float* ar   = (const float*)d_in[5];
    const float* ae   = (const float*)d_in[6];
    const float* gb   = (const float*)d_in[7];
    const float* Wih  = (const float*)d_in[8];
    const float* Whh  = (const float*)d_in[9];
    const float* bih  = (const float*)d_in[10];
    const float* bhh  = (const float*)d_in[11];
    const float* Wfc  = (const float*)d_in[12];
    const float* bfc  = (const float*)d_in[13];
    const int*   src  = (const int*)d_in[14];
    const int*   dst  = (const int*)d_in[15];
    float* out = (float*)d_out;

    // ws layout
    int* rp = (int*)d_ws;                               // [301] (pad to 320)
    unsigned* pk = (unsigned*)(rp + 320);               // [9600]
    float* Spart = (float*)(pk + E_);                   // [38 * 1152]
    float* ewT   = Spart + (long)NCH_ * G_ * H_;        // [9600 * 384]

    prep_kernel<<<901, 1024, 0, stream>>>(ew, src, dst, ewT, rp, pk);
    gat_kernel<<<NG_ * NCH_, 512, 0, stream>>>(x, ewT, Wn, We, al, ar, ae, rp, pk, Spart);
    fc_kernel<<<(B_ * OUTB_ + 255) / 256, 256, 0, stream>>>(Spart, Wn, gb, Wih, bih,
                                                            Whh, bhh, Wfc, bfc, out);
}

// Round 16
// 43.796 us; speedup vs baseline: 3.0121x; 1.6424x over previous
//
#include <hip/hip_runtime.h>
#include <math.h>

#define B_ 16
#define T_ 24
#define G_ 384
#define N_ 300
#define E_ 9600
#define H_ 3
#define F_ 8
#define HF_ 24
#define GRUH_ 16
#define OUTB_ 7200   // NUM_AIRPORTS * HORIZON
#define NW_ 16       // waves in csr block
#define TPB_ 640     // gat block threads (10 waves)

// ====== K1: CSR build with per-wave sub-histograms (validated R12) ==================
__global__ __launch_bounds__(1024) void csr_kernel(
    const int* __restrict__ src, const int* __restrict__ dst,
    int* __restrict__ rp, unsigned* __restrict__ pk)
{
    __shared__ int cnt[NW_ * N_];
    __shared__ int tot[N_];
    __shared__ int rps[N_ + 1];
    const int tid = threadIdx.x;
    const int w = tid >> 6;

    for (int i = tid; i < NW_ * N_; i += 1024) cnt[i] = 0;
    __syncthreads();
    for (int i = tid; i < E_; i += 1024) atomicAdd(&cnt[w * N_ + dst[i]], 1);
    __syncthreads();
    if (tid < N_) {
        int run = 0;
        #pragma unroll
        for (int k = 0; k < NW_; ++k) {
            int t = cnt[k * N_ + tid];
            cnt[k * N_ + tid] = run;
            run += t;
        }
        tot[tid] = run;
    }
    __syncthreads();
    if (tid < 64) {
        int base = 0;
        for (int c = 0; c < 5; ++c) {
            int i = c * 64 + tid;
            int orig = (i < N_) ? tot[i] : 0;
            int v = orig;
            #pragma unroll
            for (int o = 1; o < 64; o <<= 1) {
                int u = __shfl_up(v, o, 64);
                if (tid >= o) v += u;
            }
            if (i < N_) rps[i] = base + v - orig;
            base += __shfl(v, 63, 64);
        }
        if (tid == 0) rps[N_] = base;
    }
    __syncthreads();
    for (int i = tid; i <= N_; i += 1024) rp[i] = rps[i];
    for (int i = tid; i < E_; i += 1024) {
        int d = dst[i];
        int pos = rps[d] + atomicAdd(&cnt[w * N_ + d], 1);
        pk[pos] = (unsigned)i | ((unsigned)src[i] << 17);
    }
}

// ====== K2: EdgeGAT, 1 block/graph: coalesced staging, ALL gathers in LDS ===========
__global__ __launch_bounds__(TPB_) void gat_kernel(
    const float* __restrict__ x, const float* __restrict__ ew,
    const float* __restrict__ Wn, const float* __restrict__ We,
    const float* __restrict__ al, const float* __restrict__ ar,
    const float* __restrict__ ae,
    const int* __restrict__ rp_g, const unsigned* __restrict__ pk_g,
    float* __restrict__ S)
{
    __shared__ float ews[E_];          // edge weights, STAGED COALESCED (graph-major)
    __shared__ unsigned pkl[E_];       // packed (eid | src<<17), dst-sorted
    __shared__ float xs[N_];
    __shared__ int rp_l[N_ + 1];
    __shared__ float cf[9];
    __shared__ float Sred[10][3];

    const int g = blockIdx.x;
    const int tid = threadIdx.x;
    const long base_e = (long)g * E_;

    // coalesced float4/uint4 staging (the random gather moves to LDS below)
    const float4* ew4 = (const float4*)(ew + base_e);
    float4* ews4 = (float4*)ews;
    for (int i = tid; i < E_ / 4; i += TPB_) ews4[i] = ew4[i];
    const uint4* pk4 = (const uint4*)pk_g;
    uint4* pkl4 = (uint4*)pkl;
    for (int i = tid; i < E_ / 4; i += TPB_) pkl4[i] = pk4[i];
    for (int i = tid; i < N_; i += TPB_) xs[i] = x[g * N_ + i];
    for (int i = tid; i <= N_; i += TPB_) rp_l[i] = rp_g[i];
    if (tid < H_) {
        int h = tid;
        float cl = 0.f, cr = 0.f, ce = 0.f;
        #pragma unroll
        for (int f = 0; f < F_; ++f) {
            float wn = Wn[h * F_ + f];
            cl += wn * al[h * F_ + f];
            cr += wn * ar[h * F_ + f];
            ce += We[h * F_ + f] * ae[h * F_ + f];
        }
        cf[h] = cl; cf[3 + h] = cr; cf[6 + h] = ce;
    }
    __syncthreads();

    float n0 = 0.f, d0 = 0.f, n1 = 0.f, d1 = 0.f, n2 = 0.f, d2 = 0.f;
    if (tid < 2 * N_) {
        const int n = tid >> 1;
        const int half = tid & 1;
        const float xd = xs[n];
        const float c0l = cf[0], c1l = cf[1], c2l = cf[2];
        const float c0r = cf[3], c1r = cf[4], c2r = cf[5];
        const float c0e = cf[6], c1e = cf[7], c2e = cf[8];
        const int p1 = rp_l[n + 1];
        for (int p = rp_l[n] + half; p < p1; p += 2) {
            unsigned pkv = pkl[p];                 // LDS
            float w = ews[pkv & 0x1FFFFu];         // LDS (random bank, ~2-way)
            float xsv = xs[pkv >> 17];             // LDS
            float e0 = fmaf(xsv, c0l, fmaf(xd, c0r, w * c0e)); e0 = e0 > 0.f ? e0 : 0.2f * e0;
            float e1 = fmaf(xsv, c1l, fmaf(xd, c1r, w * c1e)); e1 = e1 > 0.f ? e1 : 0.2f * e1;
            float e2 = fmaf(xsv, c2l, fmaf(xd, c2r, w * c2e)); e2 = e2 > 0.f ? e2 : 0.2f * e2;
            float p0 = __expf(e0), pe1 = __expf(e1), pe2 = __expf(e2);
            d0 += p0;  n0 += p0 * xsv;
            d1 += pe1; n1 += pe1 * xsv;
            d2 += pe2; n2 += pe2 * xsv;
        }
    }
    // combine the node's two half-threads
    n0 += __shfl_xor(n0, 1); d0 += __shfl_xor(d0, 1);
    n1 += __shfl_xor(n1, 1); d1 += __shfl_xor(d1, 1);
    n2 += __shfl_xor(n2, 1); d2 += __shfl_xor(d2, 1);
    float a0 = 0.f, a1 = 0.f, a2 = 0.f;
    if (tid < 2 * N_ && (tid & 1) == 0) {
        a0 = d0 > 0.f ? n0 / d0 : 0.f;
        a1 = d1 > 0.f ? n1 / d1 : 0.f;
        a2 = d2 > 0.f ? n2 / d2 : 0.f;
    }
    for (int o = 32; o; o >>= 1) {
        a0 += __shfl_down(a0, o);
        a1 += __shfl_down(a1, o);
        a2 += __shfl_down(a2, o);
    }
    const int wave = tid >> 6, lane = tid & 63;
    if (lane == 0) { Sred[wave][0] = a0; Sred[wave][1] = a1; Sred[wave][2] = a2; }
    __syncthreads();
    if (tid < 3) {
        float s = 0.f;
        #pragma unroll
        for (int w2 = 0; w2 < TPB_ / 64; ++w2) s += Sred[w2][tid];
        S[g * 3 + tid] = s;
    }
}

// ====== K3: FC with replicated-GRU prologue (CPB=1 S layout) ========================
__global__ __launch_bounds__(256) void fc_kernel(
    const float* __restrict__ S, const float* __restrict__ Wn,
    const float* __restrict__ gb, const float* __restrict__ Wih,
    const float* __restrict__ bih, const float* __restrict__ Whh,
    const float* __restrict__ bhh, const float* __restrict__ Wfc,
    const float* __restrict__ bfc, float* __restrict__ out)
{
    __shared__ float S2[2][T_][H_];
    __shared__ float hS[2][GRUH_];
    const int tid = threadIdx.x;
    const int idx0 = blockIdx.x * 256;
    const int b0 = idx0 / OUTB_;

    if (tid < 2 * T_ * H_) {
        const int grp = tid / (T_ * H_);
        const int rem = tid - grp * (T_ * H_);
        const int t = rem / H_, h = rem - t * H_;
        const int bb = b0 + grp;
        float s = 0.f;
        if (bb < B_) s = S[(bb * T_ + t) * H_ + h];
        S2[grp][t][h] = s * (1.0f / N_);
    }
    __syncthreads();

    if (tid < 64) {
        const int grp = tid >> 4;
        const int u = tid & 15;
        const int gbase = tid & ~15;
        const bool active = (grp < 2) && (b0 + grp < B_);
        const int sgrp = active ? grp : 0;

        float whr[GRUH_], whz[GRUH_], whn[GRUH_];
        #pragma unroll
        for (int k = 0; k < GRUH_; ++k) {
            whr[k] = Whh[u * GRUH_ + k];
            whz[k] = Whh[(16 + u) * GRUH_ + k];
            whn[k] = Whh[(32 + u) * GRUH_ + k];
        }
        const float bhr = bhh[u], bhz = bhh[16 + u], bhn = bhh[32 + u];

        float A[3][3], C[3];
        #pragma unroll
        for (int r = 0; r < 3; ++r) {
            const int j = r * 16 + u;
            float cc = bih[j];
            A[r][0] = A[r][1] = A[r][2] = 0.f;
            #pragma unroll
            for (int k = 0; k < HF_; ++k) {
                float wk = Wih[j * HF_ + k];
                cc += wk * gb[k];
                A[r][k >> 3] += wk * Wn[k];
            }
            C[r] = cc;
        }

        float h = 0.f;
        for (int t = 0; t < T_; ++t) {
            float S0 = S2[sgrp][t][0], S1 = S2[sgrp][t][1], Sv2 = S2[sgrp][t][2];
            float gr = C[0] + A[0][0] * S0 + A[0][1] * S1 + A[0][2] * Sv2;
            float gz = C[1] + A[1][0] * S0 + A[1][1] * S1 + A[1][2] * Sv2;
            float gn = C[2] + A[2][0] * S0 + A[2][1] * S1 + A[2][2] * Sv2;
            float hr = bhr, hz = bhz, hn = bhn;
            #pragma unroll
            for (int k = 0; k < GRUH_; ++k) {
                float hk = __shfl(h, gbase + k, 64);
                hr += whr[k] * hk;
                hz += whz[k] * hk;
                hn += whn[k] * hk;
            }
            float r = 1.f / (1.f + __expf(-(gr + hr)));
            float z = 1.f / (1.f + __expf(-(gz + hz)));
            float nn = tanhf(gn + r * hn);
            h = (1.f - z) * nn + z * h;
        }
        if (active) hS[grp][u] = h;
    }
    __syncthreads();

    const int idx = idx0 + tid;
    if (idx < B_ * OUTB_) {
        const int b = idx / OUTB_, o = idx - b * OUTB_;
        const float4* wr = (const float4*)(Wfc + (long)o * GRUH_);
        const float* hr = hS[b - b0];
        float4 w0 = wr[0], w1 = wr[1], w2 = wr[2], w3 = wr[3];
        float acc = bfc[o];
        acc += hr[0]  * w0.x + hr[1]  * w0.y + hr[2]  * w0.z + hr[3]  * w0.w;
        acc += hr[4]  * w1.x + hr[5]  * w1.y + hr[6]  * w1.z + hr[7]  * w1.w;
        acc += hr[8]  * w2.x + hr[9]  * w2.y + hr[10] * w2.z + hr[11] * w2.w;
        acc += hr[12] * w3.x + hr[13] * w3.y + hr[14] * w3.z + hr[15] * w3.w;
        out[idx] = acc;
    }
}

extern "C" void kernel_launch(void* const* d_in, const int* in_sizes, int n_in,
                              void* d_out, int out_size, void* d_ws, size_t ws_size,
                              hipStream_t stream) {
    const float* x    = (const float*)d_in[0];
    const float* ew   = (const float*)d_in[1];
    const float* Wn   = (const float*)d_in[2];
    const float* We   = (const float*)d_in[3];
    const float* al   = (const float*)d_in[4];
    const float* ar   = (const float*)d_in[5];
    const float* ae   = (const float*)d_in[6];
    const float* gb   = (const float*)d_in[7];
    const float* Wih  = (const float*)d_in[8];
    const float* Whh  = (const float*)d_in[9];
    const float* bih  = (const float*)d_in[10];
    const float* bhh  = (const float*)d_in[11];
    const float* Wfc  = (const float*)d_in[12];
    const float* bfc  = (const float*)d_in[13];
    const int*   src  = (const int*)d_in[14];
    const int*   dst  = (const int*)d_in[15];
    float* out = (float*)d_out;

    // ws layout
    int* rp = (int*)d_ws;                               // [301] (pad to 320)
    unsigned* pk = (unsigned*)(rp + 320);               // [9600]
    float* S = (float*)(pk + E_);                       // [384*3]

    csr_kernel<<<1, 1024, 0, stream>>>(src, dst, rp, pk);
    gat_kernel<<<G_, TPB_, 0, stream>>>(x, ew, Wn, We, al, ar, ae, rp, pk, S);
    fc_kernel<<<(B_ * OUTB_ + 255) / 256, 256, 0, stream>>>(S, Wn, gb, Wih, bih,
                                                            Whh, bhh, Wfc, bfc, out);
}